// Round 7
// baseline (7842.831 us; speedup 1.0000x reference)
//
#include <hip/hip_runtime.h>
#include <cstddef>

// DifferentiableRollout: x_{t+1} = x + DT * ( tanh([x,u]@W1 + b1) @ W2 + b2 )
// B=1024, T=200, SD=64, CD=32, H=512.  fp32 only (R0: fp32 reorder noise
// alone -> absmax 0.25 of 1.245 threshold; bf16 would amplify past it).
//
// R7 = R6 with the compile fix: __exp2f (CUDA-ism, doesn't exist in HIP
// device code) -> __builtin_amdgcn_exp2f (emits v_exp_f32).
//
// R6 design notes:
//   Allocator history: R3/R4 (512 thr, 160 w-regs) -> scratch spill, 33 GB
//   HBM thrash.  R5 (1024 thr, 80 w-regs) -> compiler chose a 64-reg budget
//   (VGPR_Count=60) and SANK the weight loads into the t-loop: ~21 TB/s of
//   L2 re-streaming, VALU stalled on vmcnt.  Fix here:
//   (a) amdgpu_waves_per_eu(4,4): 16 waves/block = 4/EU exactly -> 128-VGPR
//       budget >= ~110 demand;
//   (b) asm volatile "+v" pins on each weight element: the asm is the only
//       def of the value used in the loop -> loads cannot be rematerialized;
//   (c) branch-free tanh: t=exp2(2x*log2e); tanh=1-2/(t+1) with rcp+1NR
//       (~8 VALU, abs err ~2e-7 vs the 0.25 fp32-reorder noise floor);
//   (d) GEMM2 inner products as explicit fmaf chains (guaranteed v_fmac);
//   (e) tanh split: g0 finishes rows 0,1; g1 rows 2,3 (balanced);
//   (f) #pragma unroll 1 on the t-loop (unrolling would double pressure).

constexpr int B_  = 1024;
constexpr int T_  = 200;
constexpr int SD_ = 64;
constexpr int CD_ = 32;
constexpr int H_  = 512;
constexpr int KD_ = SD_ + CD_;   // 96
constexpr float DT_ = 0.1f;
constexpr int ROWS_ = 4;
constexpr int THREADS_ = 1024;
constexpr int KHALF_ = 48;       // K split per g
constexpr int CHUNK_ = 32;       // W2 rows per wave (H / 16 waves)

// branch-free tanh: clamp, v_exp_f32, rcp + 1 Newton.
// abs error ~2e-7 -- far below the rollout's fp32-reorder noise floor.
__device__ __forceinline__ float fast_tanh(float x) {
    x = fminf(10.f, fmaxf(-10.f, x));                              // v_med3
    const float t = __builtin_amdgcn_exp2f(x * 2.88539008177793f); // e^{2x}
    const float d = t + 1.f;
    float r = __builtin_amdgcn_rcpf(d);
    r = r * (2.f - d * r);                            // 1 Newton: ~2^-22
    return fmaf(-2.f, r, 1.f);                        // 1 - 2/(t+1)
}

__global__ __launch_bounds__(THREADS_)
__attribute__((amdgpu_waves_per_eu(4, 4)))
void rollout_split_kernel(
    const float* __restrict__ x0,     // [B, SD]
    const float* __restrict__ ctrl,   // [B, T, CD]
    const float* __restrict__ W1,     // [KD, H]
    const float* __restrict__ b1,     // [H]
    const float* __restrict__ W2,     // [H, SD]
    const float* __restrict__ b2,     // [SD]
    float* __restrict__ out)          // [B, T+1, SD]
{
    __shared__ float xcT[KD_][ROWS_];        // state+control, transposed (16B rows)
    __shared__ float part1[ROWS_][H_];       // GEMM1 cross-half partials
    __shared__ float hbuf[ROWS_][H_];        // activations
    __shared__ float part2[ROWS_][16][SD_];  // GEMM2 partials [r][wv][s]

    const int tid = threadIdx.x;
    const int r0  = blockIdx.x * ROWS_;

    // ---- GEMM1 mapping: half-column of W1 in registers ----
    const int j     = tid & (H_ - 1);   // 0..511
    const int g     = tid >> 9;         // 0 or 1 (wave-uniform)
    const int kbase = g * KHALF_;
    float w1p[KHALF_];
    #pragma unroll
    for (int i = 0; i < KHALF_; ++i)
        w1p[i] = W1[(size_t)(kbase + i) * H_ + j];       // coalesced
    #pragma unroll
    for (int i = 0; i < KHALF_; ++i)
        asm volatile("" : "+v"(w1p[i]));                  // pin: no sink/remat

    // ---- GEMM2 mapping: 32-row W2 chunk per wave ----
    const int wv = tid >> 6;            // 0..15 (wave id)
    const int sl = tid & 63;
    const int jb = wv * CHUNK_;
    float w2p[CHUNK_];
    #pragma unroll
    for (int i = 0; i < CHUNK_; ++i)
        w2p[i] = W2[(size_t)(jb + i) * SD_ + sl];        // coalesced
    #pragma unroll
    for (int i = 0; i < CHUNK_; ++i)
        asm volatile("" : "+v"(w2p[i]));                  // pin: no sink/remat

    const float bj = b1[j];

    // reduce/update mapping (tid < 256)
    const int rf = (tid >> 6) & 3;
    const int sf = tid & 63;
    const float bs = b2[sf];

    // ctrl loader: tids [512, 640)
    const int  lt = tid - 512;
    const bool loader = (lt >= 0) && (lt < ROWS_ * CD_);
    const int  lr = (lt >> 5) & 3;
    const int  lc = lt & 31;
    const size_t ctrl_base = (size_t)(r0 + lr) * T_ * CD_ + lc;

    // ---- init: x0 into xcT + states[:,0,:], ctrl[0] into xcT ----
    if (tid < ROWS_ * SD_) {
        const float v = x0[(size_t)(r0 + rf) * SD_ + sf];
        xcT[sf][rf] = v;
        out[(size_t)(r0 + rf) * (T_ + 1) * SD_ + sf] = v;
    }
    if (loader) xcT[SD_ + lc][lr] = ctrl[ctrl_base];
    __syncthreads();

    #pragma unroll 1
    for (int t = 0; t < T_; ++t) {
        // ---- prefetch next step's controls into a register ----
        float cpre = 0.f;
        if (loader && (t + 1 < T_))
            cpre = ctrl[ctrl_base + (size_t)(t + 1) * CD_];

        // ---- GEMM1 rank-48 partials: 4 rows per thread ----
        float a0 = 0.f, a1 = 0.f, a2 = 0.f, a3 = 0.f;
        #pragma unroll
        for (int i = 0; i < KHALF_; ++i) {
            const float4 xv = *(const float4*)&xcT[kbase + i][0];  // broadcast
            const float  w  = w1p[i];
            a0 = fmaf(xv.x, w, a0);
            a1 = fmaf(xv.y, w, a1);
            a2 = fmaf(xv.z, w, a2);
            a3 = fmaf(xv.w, w, a3);
        }
        // exchange: g0 finishes rows 0,1 (needs g1's a0,a1); g1 rows 2,3.
        if (g == 0) {
            part1[2][j] = a2;  part1[3][j] = a3;   // lane-consecutive
        } else {
            part1[0][j] = a0;  part1[1][j] = a1;
        }
        __syncthreads();   // A: part1 visible; all xcT reads for step t done

        if (g == 0) {
            hbuf[0][j] = fast_tanh(bj + a0 + part1[0][j]);
            hbuf[1][j] = fast_tanh(bj + a1 + part1[1][j]);
        } else {
            hbuf[2][j] = fast_tanh(bj + a2 + part1[2][j]);
            hbuf[3][j] = fast_tanh(bj + a3 + part1[3][j]);
            if (loader && (t + 1 < T_))
                xcT[SD_ + lc][lr] = cpre;   // safe: step-t xcT reads done at A
        }
        __syncthreads();   // B: hbuf visible

        // ---- GEMM2 rank-32 partials: wave wv covers j in [jb, jb+32) ----
        #pragma unroll
        for (int r = 0; r < ROWS_; ++r) {
            float p = 0.f;
            #pragma unroll
            for (int i4 = 0; i4 < CHUNK_; i4 += 4) {
                const float4 hv = *(const float4*)&hbuf[r][jb + i4];  // broadcast
                p = fmaf(hv.x, w2p[i4],     p);
                p = fmaf(hv.y, w2p[i4 + 1], p);
                p = fmaf(hv.z, w2p[i4 + 2], p);
                p = fmaf(hv.w, w2p[i4 + 3], p);
            }
            part2[r][wv][sl] = p;       // lane-consecutive: conflict-free
        }
        __syncthreads();   // C: part2 visible

        // ---- 16-chunk reduce + state update: tid < 256 ----
        if (tid < ROWS_ * SD_) {
            float acc = part2[rf][0][sf];
            #pragma unroll
            for (int c = 1; c < 16; ++c) acc += part2[rf][c][sf];
            const float xnew = xcT[sf][rf] + DT_ * (acc + bs);
            xcT[sf][rf] = xnew;
            out[(size_t)(r0 + rf) * (T_ + 1) * SD_ + (size_t)(t + 1) * SD_ + sf] = xnew;
        }
        __syncthreads();   // D: new state visible; part2 reads done
    }
}

extern "C" void kernel_launch(void* const* d_in, const int* in_sizes, int n_in,
                              void* d_out, int out_size, void* d_ws, size_t ws_size,
                              hipStream_t stream) {
    const float* x0   = (const float*)d_in[0];
    const float* ctrl = (const float*)d_in[1];
    const float* W1   = (const float*)d_in[2];
    const float* b1   = (const float*)d_in[3];
    const float* W2   = (const float*)d_in[4];
    const float* b2   = (const float*)d_in[5];
    float* out = (float*)d_out;

    dim3 grid(B_ / ROWS_);      // 256 blocks -> 1 per CU (persistent)
    dim3 block(THREADS_);
    rollout_split_kernel<<<grid, block, 0, stream>>>(x0, ctrl, W1, b1, W2, b2, out);
}